// Round 18
// baseline (181.067 us; speedup 1.0000x reference)
//
#include <hip/hip_runtime.h>
#include <hip/hip_bf16.h>
#include <stdint.h>

// Problem constants (fixed by setup_inputs)
#define B_   64
#define H_   512
#define W_   512
#define S_N  1024      // n_segments
#define E_N  768       // embed_dim
#define K_N  768       // C*box*box = 3*16*16
#define HALF 8

typedef short bf16x8 __attribute__((ext_vector_type(8)));
typedef float f32x4  __attribute__((ext_vector_type(4)));
typedef float f32x4u __attribute__((ext_vector_type(4), aligned(4)));  // 4B-aligned float4

__device__ __forceinline__ unsigned short f2bf(float f) {
  union { float f; unsigned u; } v; v.f = f;
  unsigned u = v.u;
  u += 0x7FFF + ((u >> 16) & 1);   // RNE
  return (unsigned short)(u >> 16);
}

// ------ Phase 1 (merged): per-(b,s) packed sums (blocks 0..1023) +
//        conv_w fp32->bf16 (blocks 1024..1599) ---------------------------------
__global__ void k_accum_convw(const int* __restrict__ seg,
                              unsigned long long* __restrict__ partials,
                              const float* __restrict__ w,
                              unsigned short* __restrict__ wb) {
  __shared__ unsigned long long ls[S_N];
  const int bid = blockIdx.x;
  const int tid = threadIdx.x;
  if (bid >= 1024) {                 // conv_w conversion: 147,456 float4s
    int idx = (bid - 1024) * 256 + tid;
    float4 v = ((const float4*)w)[idx];
    ushort4 o;
    o.x = f2bf(v.x); o.y = f2bf(v.y); o.z = f2bf(v.z); o.w = f2bf(v.w);
    ((ushort4*)wb)[idx] = o;
    return;
  }
  const int xblk = bid & 15;         // 0..15
  const int b    = bid >> 4;         // 0..63
  for (int i = tid; i < S_N; i += 256) ls[i] = 0ULL;
  __syncthreads();
  const int pix0 = xblk * 16384;
  const int4* segb = (const int4*)(seg + (size_t)b * (H_ * W_) + pix0);
  for (int it = 0; it < 16; ++it) {
    int4 s4 = segb[it * 256 + tid];
    int p0 = pix0 + (it * 256 + tid) * 4;
    unsigned long long base = ((unsigned long long)(unsigned)(p0 >> 9) << 39)
                            | ((unsigned long long)(unsigned)(p0 & (W_ - 1)) << 15)
                            | 1ULL;
    #pragma unroll
    for (int j = 0; j < 4; ++j) {
      int s = (&s4.x)[j];
      s = ((unsigned)s < S_N) ? s : 0;
      atomicAdd(&ls[s], base + ((unsigned long long)j << 15));
    }
  }
  __syncthreads();
  unsigned long long* gp = partials + ((size_t)b * 16 + xblk) * S_N;
  for (int s = tid; s < S_N; s += 256) gp[s] = ls[s];
}

// ------ Phase 2: FUSED gather-GEMM with register prefetch (T14 both operands) -
// r17 lesson: fused gather correct & FETCH=21MB, but gather+convert+write sat
// SERIALLY in the tile loop (153us). Fix: issue tile k+1's A-gather (8 coalesced
// loads) and B-rows (4 loads, reg-staged — no global_load_lds left, so no
// manual vmcnt ledger) BEFORE tile k's MFMA phase; loads land under the MFMAs.
// Post-barrier residue = convert + 12 ds_write_b128 + publish barrier only.
// Registers only -> LDS stays 64KB+pc -> 2 blocks/CU retained. Per-thread
// gather context (rows, corners, base ptrs) is loop-invariant, hoisted once.
__global__ __launch_bounds__(512) void k_gemmfg2(
    const float* __restrict__ img,
    const unsigned long long* __restrict__ partials,
    const unsigned short* __restrict__ Bmat,
    float* __restrict__ out) {
  __shared__ unsigned short As[256 * 64];   // 32 KB
  __shared__ unsigned short Bs[256 * 64];   // 32 KB
  __shared__ int2 pc[256];                  // per-patch min corner
  const int tid  = threadIdx.x;
  const int wave = tid >> 6;
  const int lane = tid & 63;

  // bijective XCD remap: 768 blocks = 8 XCDs x 96; bn fastest
  const int virt = (blockIdx.x & 7) * 96 + (blockIdx.x >> 3);
  const int bm = virt / 3;
  const int bn = virt - bm * 3;
  const int gm0 = bm * 256;
  const int gn0 = bn * 256;
  const int b   = bm >> 2;                  // all 256 patches share batch b
  const float* ib = img + (size_t)b * 3 * H_ * W_;

  // ---- one-time: coords for this block's 256 patches ----
  if (tid < 256) {
    const int s = (gm0 + tid) & (S_N - 1);
    unsigned c = 0, sx = 0, sy = 0;
    #pragma unroll
    for (int x = 0; x < 16; ++x) {
      unsigned long long v = partials[((size_t)b * 16 + x) * S_N + s];
      c  += (unsigned)(v & 0x7FFFULL);
      sx += (unsigned)((v >> 15) & 0xFFFFFFULL);
      sy += (unsigned)(v >> 39);
    }
    int xmin = 0, ymin = 0;
    if (c > 0) {
      float cf = (float)c;
      xmin = (int)floorf((float)sx / cf);   // IEEE f32 div of exact ints == ref
      ymin = (int)floorf((float)sy / cf);
    }
    pc[tid] = make_int2(xmin - HALF, ymin - HALF);
  }

  const int wr = wave >> 2;          // 0..1
  const int wc = wave & 3;           // 0..3
  const int rlo  = lane & 15;
  const int rsel = lane & 7;
  const int sub  = lane >> 4;
  int swz[2];
  swz[0] = ((0 + sub) ^ rsel) * 8;
  swz[1] = ((4 + sub) ^ rsel) * 8;

  f32x4 acc[8][4];
  #pragma unroll
  for (int i = 0; i < 8; ++i)
    #pragma unroll
    for (int j = 0; j < 4; ++j)
      acc[i][j] = (f32x4){0.f, 0.f, 0.f, 0.f};

  __syncthreads();                   // pc ready

  // ---- loop-invariant per-thread gather context ----
  // seg = i*512 + tid -> row = i*64 + (tid>>3), chunk cc0 = tid&7 (fixed).
  const int cc0 = tid & 7;
  const int rsub = tid >> 3;                  // 0..63
  int2 pi[4]; bool inti[4];
  const float* arow[4];
  const unsigned short* brow[4];
  #pragma unroll
  for (int i = 0; i < 4; ++i) {
    int row = i * 64 + rsub;
    int2 p = pc[row];
    pi[i] = p;
    inti[i] = (p.x >= 0 && p.x <= W_ - 16 && p.y >= 0 && p.y <= H_ - 16);
    arow[i] = ib + (size_t)(inti[i] ? p.y : 0) * W_ + (inti[i] ? p.x : 0);
    brow[i] = Bmat + (size_t)(gn0 + row) * K_N + (cc0 ^ (row & 7)) * 8;
  }

  f32x4 ga[4][2];
  bf16x8 gb[4];

  // issue next tile's loads into registers (coalesced: 8 lanes = 1 patch)
  auto issue = [&](int k0) {
    const int k = k0 + cc0 * 8;
    const int ch = k >> 8, h = (k >> 4) & 15, w0 = k & 15;
    const int roff = ((ch << 9) + h) * W_ + w0;
    #pragma unroll
    for (int i = 0; i < 4; ++i) {
      if (inti[i]) {
        const float* rp = arow[i] + roff;
        ga[i][0] = *(const f32x4u*)rp;
        ga[i][1] = *(const f32x4u*)(rp + 4);
      } else {                       // rare edge patch: masked scalar
        int y = pi[i].y + h;
        int x0 = pi[i].x + w0;
        bool yok = (unsigned)y < H_;
        const float* rp = ib + (size_t)((ch << 9) + (yok ? y : 0)) * W_;
        #pragma unroll
        for (int j = 0; j < 4; ++j) {
          int x = x0 + j;
          ga[i][0][j] = (yok && (unsigned)x < W_) ? rp[x] : 0.f;
        }
        #pragma unroll
        for (int j = 0; j < 4; ++j) {
          int x = x0 + 4 + j;
          ga[i][1][j] = (yok && (unsigned)x < W_) ? rp[x] : 0.f;
        }
      }
      gb[i] = *(const bf16x8*)(brow[i] + k0);
    }
  };

  // convert + write the prefetched tile into LDS (T2 swizzle on A)
  auto writeTile = [&]() {
    #pragma unroll
    for (int i = 0; i < 4; ++i) {
      int row = i * 64 + rsub;
      bf16x8 t;
      t[0] = (short)f2bf(ga[i][0][0]); t[1] = (short)f2bf(ga[i][0][1]);
      t[2] = (short)f2bf(ga[i][0][2]); t[3] = (short)f2bf(ga[i][0][3]);
      t[4] = (short)f2bf(ga[i][1][0]); t[5] = (short)f2bf(ga[i][1][1]);
      t[6] = (short)f2bf(ga[i][1][2]); t[7] = (short)f2bf(ga[i][1][3]);
      *(bf16x8*)&As[row * 64 + ((cc0 ^ (row & 7)) << 3)] = t;
      *(bf16x8*)&Bs[(i * 512 + tid) * 8] = gb[i];
    }
  };

  // Prologue: tile 0 loaded + written, published.
  issue(0);
  writeTile();
  __syncthreads();

  for (int kt = 0; kt < 12; ++kt) {
    if (kt + 1 < 12) issue((kt + 1) * 64);      // lands under the MFMAs below
    __builtin_amdgcn_sched_barrier(0);          // pin load-issue above MFMA

    #pragma unroll
    for (int kk = 0; kk < 2; ++kk) {
      bf16x8 av[8], bv[4];
      #pragma unroll
      for (int mi = 0; mi < 8; ++mi)
        av[mi] = *(const bf16x8*)&As[(wr * 128 + mi * 16 + rlo) * 64 + swz[kk]];
      #pragma unroll
      for (int ni = 0; ni < 4; ++ni)
        bv[ni] = *(const bf16x8*)&Bs[(wc * 64 + ni * 16 + rlo) * 64 + swz[kk]];
      __builtin_amdgcn_s_setprio(1);
      #pragma unroll
      for (int mi = 0; mi < 8; ++mi)
        #pragma unroll
        for (int ni = 0; ni < 4; ++ni)
          acc[mi][ni] = __builtin_amdgcn_mfma_f32_16x16x32_bf16(
              av[mi], bv[ni], acc[mi][ni], 0, 0, 0);
      __builtin_amdgcn_s_setprio(0);
    }

    if (kt + 1 < 12) {
      __syncthreads();               // all reads of As/Bs done
      writeTile();                   // compiler inserts vmcnt waits for ga/gb
      __syncthreads();               // publish (drains lgkm)
    }
  }

  // Epilogue: C/D layout col=lane&15, row=(lane>>4)*4+reg
  const int row0 = gm0 + wr * 128 + (lane >> 4) * 4;
  const int col0 = gn0 + wc * 64 + (lane & 15);
  #pragma unroll
  for (int mi = 0; mi < 8; ++mi)
    #pragma unroll
    for (int ni = 0; ni < 4; ++ni)
      #pragma unroll
      for (int r = 0; r < 4; ++r)
        out[(size_t)(row0 + mi * 16 + r) * E_N + (col0 + ni * 16)] = acc[mi][ni][r];
}

extern "C" void kernel_launch(void* const* d_in, const int* in_sizes, int n_in,
                              void* d_out, int out_size, void* d_ws, size_t ws_size,
                              hipStream_t stream) {
  const float* img = (const float*)d_in[0];
  const int*   seg = (const int*)d_in[1];
  const float* cw  = (const float*)d_in[2];
  float* out = (float*)d_out;
  char* ws = (char*)d_ws;

  unsigned long long* partials = (unsigned long long*)ws;    // 8,388,608 B
  unsigned short* Bmat = (unsigned short*)(ws + 8388608);    // 1,179,648 B

  k_accum_convw<<<1600, 256, 0, stream>>>(seg, partials, cw, Bmat);
  k_gemmfg2<<<768, 512, 0, stream>>>(img, partials, Bmat, out);
}

// Round 19
// 140.976 us; speedup vs baseline: 1.2844x; 1.2844x over previous
//
#include <hip/hip_runtime.h>
#include <hip/hip_bf16.h>
#include <stdint.h>

// Problem constants (fixed by setup_inputs)
#define B_   64
#define H_   512
#define W_   512
#define S_N  1024      // n_segments
#define E_N  768       // embed_dim
#define K_N  768       // C*box*box = 3*16*16
#define HALF 8

typedef short bf16x8 __attribute__((ext_vector_type(8)));
typedef float f32x4  __attribute__((ext_vector_type(4)));
typedef float f32x4u __attribute__((ext_vector_type(4), aligned(4)));  // 4B-aligned float4

__device__ __forceinline__ unsigned short f2bf(float f) {
  union { float f; unsigned u; } v; v.f = f;
  unsigned u = v.u;
  u += 0x7FFF + ((u >> 16) & 1);   // RNE
  return (unsigned short)(u >> 16);
}

// ------ Phase 1 (merged): per-(b,s) packed sums (blocks 0..1023) +
//        conv_w fp32->bf16 (blocks 1024..1599) ---------------------------------
__global__ void k_accum_convw(const int* __restrict__ seg,
                              unsigned long long* __restrict__ partials,
                              const float* __restrict__ w,
                              unsigned short* __restrict__ wb) {
  __shared__ unsigned long long ls[S_N];
  const int bid = blockIdx.x;
  const int tid = threadIdx.x;
  if (bid >= 1024) {                 // conv_w conversion: 147,456 float4s
    int idx = (bid - 1024) * 256 + tid;
    float4 v = ((const float4*)w)[idx];
    ushort4 o;
    o.x = f2bf(v.x); o.y = f2bf(v.y); o.z = f2bf(v.z); o.w = f2bf(v.w);
    ((ushort4*)wb)[idx] = o;
    return;
  }
  const int xblk = bid & 15;         // 0..15
  const int b    = bid >> 4;         // 0..63
  for (int i = tid; i < S_N; i += 256) ls[i] = 0ULL;
  __syncthreads();
  const int pix0 = xblk * 16384;
  const int4* segb = (const int4*)(seg + (size_t)b * (H_ * W_) + pix0);
  for (int it = 0; it < 16; ++it) {
    int4 s4 = segb[it * 256 + tid];
    int p0 = pix0 + (it * 256 + tid) * 4;
    unsigned long long base = ((unsigned long long)(unsigned)(p0 >> 9) << 39)
                            | ((unsigned long long)(unsigned)(p0 & (W_ - 1)) << 15)
                            | 1ULL;
    #pragma unroll
    for (int j = 0; j < 4; ++j) {
      int s = (&s4.x)[j];
      s = ((unsigned)s < S_N) ? s : 0;
      atomicAdd(&ls[s], base + ((unsigned long long)j << 15));
    }
  }
  __syncthreads();
  unsigned long long* gp = partials + ((size_t)b * 16 + xblk) * S_N;
  for (int s = tid; s < S_N; s += 256) gp[s] = ls[s];
}

// ------ Phase 2: FUSED gather-GEMM, dbuf LDS + 16-reg half-tile A prefetch ----
// r18 lesson: 48 prefetch regs across the MFMA phase spilled (WRITE 197->302MB)
// because acc=128 AGPR caps VGPR at 128. This version prefetches A one K-HALF
// at a time (2 chunks/thread = 16 VGPRs) and hides each half under one 32-MFMA
// sub-phase; B prefetches via global_load_lds (0 regs) into a double buffer.
// LDS is free (registers bind occupancy at 1 block/CU): As/Bs both x2 = 128KB.
// One barrier per tile. Writes target only buf^1 (last read 1 sync ago);
// half0/half1 write positions {0..3}^(r&7) / {4..7}^(r&7) are complementary.
__global__ __launch_bounds__(512) void k_gemmfg3(
    const float* __restrict__ img,
    const unsigned long long* __restrict__ partials,
    const unsigned short* __restrict__ Bmat,
    float* __restrict__ out) {
  __shared__ unsigned short As[2][256 * 64];   // 2 x 32 KB
  __shared__ unsigned short Bs[2][256 * 64];   // 2 x 32 KB
  __shared__ int2 pc[256];
  const int tid  = threadIdx.x;
  const int wave = tid >> 6;
  const int lane = tid & 63;

  // bijective XCD remap: 768 blocks = 8 XCDs x 96; bn fastest
  const int virt = (blockIdx.x & 7) * 96 + (blockIdx.x >> 3);
  const int bm = virt / 3;
  const int bn = virt - bm * 3;
  const int gm0 = bm * 256;
  const int gn0 = bn * 256;
  const int b   = bm >> 2;
  const float* ib = img + (size_t)b * 3 * H_ * W_;

  // ---- one-time: coords for this block's 256 patches ----
  if (tid < 256) {
    const int s = (gm0 + tid) & (S_N - 1);
    unsigned c = 0, sx = 0, sy = 0;
    #pragma unroll
    for (int x = 0; x < 16; ++x) {
      unsigned long long v = partials[((size_t)b * 16 + x) * S_N + s];
      c  += (unsigned)(v & 0x7FFFULL);
      sx += (unsigned)((v >> 15) & 0xFFFFFFULL);
      sy += (unsigned)(v >> 39);
    }
    int xmin = 0, ymin = 0;
    if (c > 0) {
      float cf = (float)c;
      xmin = (int)floorf((float)sx / cf);   // IEEE f32 div of exact ints == ref
      ymin = (int)floorf((float)sy / cf);
    }
    pc[tid] = make_int2(xmin - HALF, ymin - HALF);
  }

  const int wr = wave >> 2;          // 0..1
  const int wc = wave & 3;           // 0..3
  const int rlo  = lane & 15;
  const int rsel = lane & 7;
  const int sub  = lane >> 4;
  int swz[2];
  swz[0] = ((0 + sub) ^ rsel) * 8;
  swz[1] = ((4 + sub) ^ rsel) * 8;

  f32x4 acc[8][4];
  #pragma unroll
  for (int i = 0; i < 8; ++i)
    #pragma unroll
    for (int j = 0; j < 4; ++j)
      acc[i][j] = (f32x4){0.f, 0.f, 0.f, 0.f};

  __syncthreads();                   // pc ready

  // ---- loop-invariant A-gather context: 2 rows/thread, 4 threads/row ----
  // per K-half: seg' = i*512 + tid (i=0,1) -> row = seg'>>2, cd = tid&3.
  const int cd = tid & 3;
  const int r0 = tid >> 2;           // rows r0 and 128+r0
  int2 pi[2]; bool inti[2];
  const float* arow[2];
  #pragma unroll
  for (int i = 0; i < 2; ++i) {
    int row = i * 128 + r0;
    int2 p = pc[row];
    pi[i] = p;
    inti[i] = (p.x >= 0 && p.x <= W_ - 16 && p.y >= 0 && p.y <= H_ - 16);
    arow[i] = ib + (size_t)(inti[i] ? p.y : 0) * W_ + (inti[i] ? p.x : 0);
  }

  f32x4 ga[2][2];                    // 16 VGPRs live across one MFMA sub-phase

  // issue one K-half's A loads (chunk c = h*4+cd, 8 floats) into ga
  auto issueA = [&](int k0, int h) {
    const int c  = h * 4 + cd;
    const int k  = k0 + c * 8;
    const int ch = k >> 8, hh = (k >> 4) & 15, w0 = k & 15;
    const int roff = ((ch << 9) + hh) * W_ + w0;
    #pragma unroll
    for (int i = 0; i < 2; ++i) {
      if (inti[i]) {
        const float* rp = arow[i] + roff;
        ga[i][0] = *(const f32x4u*)rp;
        ga[i][1] = *(const f32x4u*)(rp + 4);
      } else {
        int y = pi[i].y + hh;
        int x0 = pi[i].x + w0;
        bool yok = (unsigned)y < H_;
        const float* rp = ib + (size_t)((ch << 9) + (yok ? y : 0)) * W_;
        #pragma unroll
        for (int j = 0; j < 4; ++j) {
          int x = x0 + j;
          ga[i][0][j] = (yok && (unsigned)x < W_) ? rp[x] : 0.f;
        }
        #pragma unroll
        for (int j = 0; j < 4; ++j) {
          int x = x0 + 4 + j;
          ga[i][1][j] = (yok && (unsigned)x < W_) ? rp[x] : 0.f;
        }
      }
    }
  };
  // convert + swizzled write of one K-half into As[buf]
  auto writeA = [&](int buf, int h) {
    const int c = h * 4 + cd;
    #pragma unroll
    for (int i = 0; i < 2; ++i) {
      int row = i * 128 + r0;
      bf16x8 t;
      #pragma unroll
      for (int j = 0; j < 4; ++j) {
        t[j]     = (short)__bfloat16_as_ushort(__float2bfloat16(ga[i][0][j]));
        t[4 + j] = (short)__bfloat16_as_ushort(__float2bfloat16(ga[i][1][j]));
      }
      *(bf16x8*)&As[buf][row * 64 + ((c ^ (row & 7)) << 3)] = t;
    }
  };
  // B staging: 4 global_load_lds (r10 partition + T2 source swizzle), 0 regs
  auto stageB = [&](int buf, int k0) {
    #pragma unroll
    for (int i = 0; i < 4; ++i) {
      int seg = i * 512 + tid;
      int row = seg >> 3;
      int csrc = (seg & 7) ^ (row & 7);
      const unsigned short* g = Bmat + (size_t)(gn0 + row) * K_N + k0 + csrc * 8;
      __builtin_amdgcn_global_load_lds((const __attribute__((address_space(1))) void*)g,
        (__attribute__((address_space(3))) void*)&Bs[buf][(i * 512 + wave * 64) * 8], 16, 0, 0);
    }
  };

#define MFMA_HALF(BUF, KK) do {                                                  \
    bf16x8 av[8], bv[4];                                                         \
    _Pragma("unroll") for (int mi = 0; mi < 8; ++mi)                             \
      av[mi] = *(const bf16x8*)&As[BUF][(wr * 128 + mi * 16 + rlo) * 64 + swz[KK]]; \
    _Pragma("unroll") for (int ni = 0; ni < 4; ++ni)                             \
      bv[ni] = *(const bf16x8*)&Bs[BUF][(wc * 64 + ni * 16 + rlo) * 64 + swz[KK]];  \
    __builtin_amdgcn_s_setprio(1);                                               \
    _Pragma("unroll") for (int mi = 0; mi < 8; ++mi)                             \
      _Pragma("unroll") for (int ni = 0; ni < 4; ++ni)                           \
        acc[mi][ni] = __builtin_amdgcn_mfma_f32_16x16x32_bf16(                   \
            av[mi], bv[ni], acc[mi][ni], 0, 0, 0);                               \
    __builtin_amdgcn_s_setprio(0);                                               \
  } while (0)

  // Prologue: tile 0 fully staged into buf 0.
  stageB(0, 0);
  issueA(0, 0); writeA(0, 0);
  issueA(0, 1); writeA(0, 1);
  asm volatile("s_waitcnt vmcnt(0) lgkmcnt(0)" ::: "memory");
  __syncthreads();

  for (int kt = 0; kt < 12; ++kt) {
    const int buf = kt & 1;
    const bool pre = (kt + 1 < 12);
    const int kn = (kt + 1) * 64;

    if (pre) { stageB(buf ^ 1, kn); issueA(kn, 0); }   // t1+t2: no-reg B, 16-reg A
    MFMA_HALF(buf, 0);                                 // t3: half0 latency hides
    if (pre) { writeA(buf ^ 1, 0); issueA(kn, 1); }    // t4+t5
    MFMA_HALF(buf, 1);                                 // t6: half1 hides
    if (pre) writeA(buf ^ 1, 1);                       // t7
    asm volatile("s_waitcnt vmcnt(0) lgkmcnt(0)" ::: "memory");  // t8: B landed, A writes done
    __syncthreads();                                   // single publish barrier
  }

  // Epilogue: C/D layout col=lane&15, row=(lane>>4)*4+reg
  const int row0 = gm0 + wr * 128 + (lane >> 4) * 4;
  const int col0 = gn0 + wc * 64 + (lane & 15);
  #pragma unroll
  for (int mi = 0; mi < 8; ++mi)
    #pragma unroll
    for (int ni = 0; ni < 4; ++ni)
      #pragma unroll
      for (int r = 0; r < 4; ++r)
        out[(size_t)(row0 + mi * 16 + r) * E_N + (col0 + ni * 16)] = acc[mi][ni][r];
#undef MFMA_HALF
}

extern "C" void kernel_launch(void* const* d_in, const int* in_sizes, int n_in,
                              void* d_out, int out_size, void* d_ws, size_t ws_size,
                              hipStream_t stream) {
  const float* img = (const float*)d_in[0];
  const int*   seg = (const int*)d_in[1];
  const float* cw  = (const float*)d_in[2];
  float* out = (float*)d_out;
  char* ws = (char*)d_ws;

  unsigned long long* partials = (unsigned long long*)ws;    // 8,388,608 B
  unsigned short* Bmat = (unsigned short*)(ws + 8388608);    // 1,179,648 B

  k_accum_convw<<<1600, 256, 0, stream>>>(seg, partials, cw, Bmat);
  k_gemmfg3<<<768, 512, 0, stream>>>(img, partials, Bmat, out);
}